// Round 2
// baseline (1499.082 us; speedup 1.0000x reference)
//
#include <hip/hip_runtime.h>
#include <hip/hip_bf16.h>
#include <math.h>

typedef __hip_bfloat16 bf16;
typedef short bf16x8 __attribute__((ext_vector_type(8)));
typedef float f32x4 __attribute__((ext_vector_type(4)));

#define GLD16(g, l)                                                            \
  __builtin_amdgcn_global_load_lds(                                            \
      (const __attribute__((address_space(1))) void*)(g),                      \
      (__attribute__((address_space(3))) void*)(l), 16, 0, 0)

// ------------------------------------------------------- f32 -> bf16 copy
__global__ void convert_f32_bf16(const float* __restrict__ in,
                                 bf16* __restrict__ out) {
  size_t i = ((size_t)blockIdx.x * 256 + threadIdx.x) * 4;
  float4 v = *(const float4*)(in + i);
  out[i + 0] = __float2bfloat16(v.x);
  out[i + 1] = __float2bfloat16(v.y);
  out[i + 2] = __float2bfloat16(v.z);
  out[i + 3] = __float2bfloat16(v.w);
}

// ----------------------------------------- f32 -> bf16 transposed weights
__global__ void transpose_f32_bf16(const float* __restrict__ in,
                                   bf16* __restrict__ out, int R, int C) {
  __shared__ bf16 tile[32][33];
  int tx = threadIdx.x & 31, ty = threadIdx.x >> 5;
  int c0 = blockIdx.x * 32, r0 = blockIdx.y * 32;
#pragma unroll
  for (int i = 0; i < 32; i += 8)
    tile[ty + i][tx] = __float2bfloat16(in[(size_t)(r0 + ty + i) * C + c0 + tx]);
  __syncthreads();
#pragma unroll
  for (int i = 0; i < 32; i += 8)
    out[(size_t)(c0 + ty + i) * R + r0 + tx] = tile[tx][ty + i];
}

// V: [4096][1024] bf16 (row = b*2048+t, col = kvh*128+d) -> VT: [16][128][2048]
__global__ void transpose_v(const bf16* __restrict__ V, bf16* __restrict__ VT) {
  __shared__ bf16 tile[32][33];
  int s = blockIdx.z, b = s >> 3, kvh = s & 7;
  int t0 = blockIdx.x * 32, d0 = blockIdx.y * 32;
  int tx = threadIdx.x & 31, ty = threadIdx.x >> 5;
#pragma unroll
  for (int i = 0; i < 32; i += 8)
    tile[ty + i][tx] = V[(size_t)(b * 2048 + t0 + ty + i) * 1024 + kvh * 128 + d0 + tx];
  __syncthreads();
#pragma unroll
  for (int i = 0; i < 32; i += 8)
    VT[((size_t)s * 128 + d0 + ty + i) * 2048 + t0 + tx] = tile[tx][ty + i];
}

// ---------------------------------------------------------------- RoPE
__global__ void rope_table_k(float* __restrict__ tab) {
  int idx = blockIdx.x * 256 + threadIdx.x;  // t*64 + i, 2048*64 total
  int t = idx >> 6, i = idx & 63;
  float theta = powf(10000.0f, -2.0f * (float)i / 128.0f);
  float ang = (float)t * theta;
  tab[idx * 2 + 0] = cosf(ang);
  tab[idx * 2 + 1] = sinf(ang);
}

__global__ void rope_apply(bf16* __restrict__ X, const float* __restrict__ tab,
                           int nheads) {
  size_t idx = (size_t)blockIdx.x * 256 + threadIdx.x;  // rows*nheads*64
  int i = (int)(idx & 63);
  size_t rest = idx >> 6;
  int h = (int)(rest % nheads);
  size_t r = rest / nheads;
  int t = (int)(r & 2047);
  float c = tab[(t * 64 + i) * 2 + 0];
  float s = tab[(t * 64 + i) * 2 + 1];
  bf16* p = X + r * ((size_t)nheads * 128) + h * 128 + 2 * i;
  float xr = __bfloat162float(p[0]), xi = __bfloat162float(p[1]);
  p[0] = __float2bfloat16(xr * c - xi * s);
  p[1] = __float2bfloat16(xr * s + xi * c);
}

// ---------------------------------------------------------------- GEMM (B^T)
// C[M][N] = A[M][K] * BT[N][K]^T ; M,N % 128 == 0, K % 32 == 0
template <typename OutT>
__global__ __launch_bounds__(256, 3) void gemm_bt(const bf16* __restrict__ A,
                                                  const bf16* __restrict__ BT,
                                                  OutT* __restrict__ C, int M,
                                                  int N, int K) {
  __shared__ bf16 As[128 * 32];
  __shared__ bf16 Bs[128 * 32];
  const int tid = threadIdx.x;
  const int lane = tid & 63, w = tid >> 6;
  const int wr = w >> 1, wc = w & 1;
  const int lr = lane & 15;
  const int ko = (lane >> 4) * 8;
  const int m0 = blockIdx.y * 128, n0 = blockIdx.x * 128;

  f32x4 acc[4][4];
#pragma unroll
  for (int m = 0; m < 4; ++m)
#pragma unroll
    for (int n = 0; n < 4; ++n)
#pragma unroll
      for (int j = 0; j < 4; ++j) acc[m][n][j] = 0.f;

  for (int k0 = 0; k0 < K; k0 += 32) {
#pragma unroll
    for (int i = 0; i < 2; ++i) {
      int c = i * 256 + tid;
      const bf16* ga = A + (size_t)(m0 + (c >> 2)) * K + k0 + (c & 3) * 8;
      const bf16* gb = BT + (size_t)(n0 + (c >> 2)) * K + k0 + (c & 3) * 8;
      GLD16(ga, As + c * 8);
      GLD16(gb, Bs + c * 8);
    }
    __syncthreads();
    bf16x8 af[4], bfr[4];
#pragma unroll
    for (int m = 0; m < 4; ++m)
      af[m] = *(const bf16x8*)(As + (wr * 64 + m * 16 + lr) * 32 + ko);
#pragma unroll
    for (int n = 0; n < 4; ++n)
      bfr[n] = *(const bf16x8*)(Bs + (wc * 64 + n * 16 + lr) * 32 + ko);
#pragma unroll
    for (int m = 0; m < 4; ++m)
#pragma unroll
      for (int n = 0; n < 4; ++n)
        acc[m][n] = __builtin_amdgcn_mfma_f32_16x16x32_bf16(af[m], bfr[n],
                                                            acc[m][n], 0, 0, 0);
    __syncthreads();
  }
#pragma unroll
  for (int m = 0; m < 4; ++m) {
    int row_base = m0 + wr * 64 + m * 16 + (lane >> 4) * 4;
#pragma unroll
    for (int n = 0; n < 4; ++n) {
      int col = n0 + wc * 64 + n * 16 + lr;
#pragma unroll
      for (int j = 0; j < 4; ++j) {
        float v = acc[m][n][j];
        if constexpr (sizeof(OutT) == 2)
          C[(size_t)(row_base + j) * N + col] = (OutT)__float2bfloat16(v);
        else
          C[(size_t)(row_base + j) * N + col] = (OutT)v;
      }
    }
  }
}

// ---------------------------------------------------------------- flash attn
// Q: [4096][4096] (roped), K: [4096][1024] (roped), VT: [16][128][2048]
// AO: [4096][4096]. Grid: 2048 blocks (b*1024 + h*32 + qt), 256 thr (4 waves),
// wave handles 16 q-rows; causal.
__global__ __launch_bounds__(256) void flash_attn(const bf16* __restrict__ Q,
                                                  const bf16* __restrict__ K,
                                                  const bf16* __restrict__ VT,
                                                  bf16* __restrict__ AO) {
  __shared__ bf16 P[4][16][64];
  int blk = blockIdx.x;
  int qt = blk & 31, h = (blk >> 5) & 31, b = blk >> 10;
  int kvh = h >> 2;
  int lane = threadIdx.x & 63, w = threadIdx.x >> 6;
  int lr = lane & 15, hi = lane >> 4, ko = hi * 8;
  int qrow0 = qt * 64 + w * 16;

  bf16x8 qf[4];
  const bf16* qbase = Q + (size_t)(b * 2048 + qrow0 + lr) * 4096 + h * 128;
#pragma unroll
  for (int kk = 0; kk < 4; ++kk) qf[kk] = *(const bf16x8*)(qbase + kk * 32 + ko);

  f32x4 O[8];
  float m_[4], l_[4];
#pragma unroll
  for (int d = 0; d < 8; ++d)
#pragma unroll
    for (int j = 0; j < 4; ++j) O[d][j] = 0.f;
#pragma unroll
  for (int j = 0; j < 4; ++j) { m_[j] = -1e30f; l_[j] = 0.f; }

  const float scale = 0.08838834764831845f;  // 1/sqrt(128)
  int qmax = qrow0 + 15;

  for (int kv0 = 0; kv0 <= qmax; kv0 += 64) {
    f32x4 S[4];
#pragma unroll
    for (int cb = 0; cb < 4; ++cb)
#pragma unroll
      for (int j = 0; j < 4; ++j) S[cb][j] = 0.f;

#pragma unroll
    for (int cb = 0; cb < 4; ++cb) {
      const bf16* kbase = K + (size_t)(b * 2048 + kv0 + cb * 16 + lr) * 1024 + kvh * 128;
#pragma unroll
      for (int kk = 0; kk < 4; ++kk) {
        bf16x8 kf = *(const bf16x8*)(kbase + kk * 32 + ko);
        S[cb] = __builtin_amdgcn_mfma_f32_16x16x32_bf16(qf[kk], kf, S[cb], 0, 0, 0);
      }
    }

    // scale + causal mask + per-row max (rows: hi*4+j, cols: cb*16+lr)
    float pm[4];
#pragma unroll
    for (int j = 0; j < 4; ++j) {
      int qr = qrow0 + hi * 4 + j;
      float mx = -1e30f;
#pragma unroll
      for (int cb = 0; cb < 4; ++cb) {
        int col = kv0 + cb * 16 + lr;
        float v = S[cb][j] * scale;
        v = (col > qr) ? -1e30f : v;
        S[cb][j] = v;
        mx = fmaxf(mx, v);
      }
      pm[j] = mx;
    }
#pragma unroll
    for (int st = 1; st < 16; st <<= 1)
#pragma unroll
      for (int j = 0; j < 4; ++j) pm[j] = fmaxf(pm[j], __shfl_xor(pm[j], st));

    float nm[4], rs[4], psum[4];
#pragma unroll
    for (int j = 0; j < 4; ++j) {
      nm[j] = fmaxf(m_[j], pm[j]);
      rs[j] = __expf(m_[j] - nm[j]);
      psum[j] = 0.f;
    }
#pragma unroll
    for (int cb = 0; cb < 4; ++cb)
#pragma unroll
      for (int j = 0; j < 4; ++j) {
        float p = __expf(S[cb][j] - nm[j]);
        S[cb][j] = p;
        psum[j] += p;
      }
#pragma unroll
    for (int st = 1; st < 16; st <<= 1)
#pragma unroll
      for (int j = 0; j < 4; ++j) psum[j] += __shfl_xor(psum[j], st);
#pragma unroll
    for (int j = 0; j < 4; ++j) {
      l_[j] = l_[j] * rs[j] + psum[j];
      m_[j] = nm[j];
    }
#pragma unroll
    for (int d = 0; d < 8; ++d)
#pragma unroll
      for (int j = 0; j < 4; ++j) O[d][j] *= rs[j];

    // P (C-layout) -> LDS -> A-layout fragments
#pragma unroll
    for (int cb = 0; cb < 4; ++cb)
#pragma unroll
      for (int j = 0; j < 4; ++j)
        P[w][hi * 4 + j][cb * 16 + lr] = __float2bfloat16(S[cb][j]);
    bf16x8 pa[2];
#pragma unroll
    for (int kk2 = 0; kk2 < 2; ++kk2)
      pa[kk2] = *(const bf16x8*)(&P[w][lr][kk2 * 32 + ko]);

#pragma unroll
    for (int d = 0; d < 8; ++d) {
      const bf16* vbase = VT + ((size_t)(b * 8 + kvh) * 128 + d * 16 + lr) * 2048 + kv0;
#pragma unroll
      for (int kk2 = 0; kk2 < 2; ++kk2) {
        bf16x8 vf = *(const bf16x8*)(vbase + kk2 * 32 + ko);
        O[d] = __builtin_amdgcn_mfma_f32_16x16x32_bf16(pa[kk2], vf, O[d], 0, 0, 0);
      }
    }
  }

#pragma unroll
  for (int j = 0; j < 4; ++j) {
    float inv = 1.0f / l_[j];
    int row = b * 2048 + qrow0 + hi * 4 + j;
#pragma unroll
    for (int d = 0; d < 8; ++d)
      AO[(size_t)row * 4096 + h * 128 + d * 16 + lr] =
          __float2bfloat16(O[d][j] * inv);
  }
}

// ---------------------------------------------------------------- launch
extern "C" void kernel_launch(void* const* d_in, const int* in_sizes, int n_in,
                              void* d_out, int out_size, void* d_ws,
                              size_t ws_size, hipStream_t stream) {
  const float* x = (const float*)d_in[0];
  const float* wq = (const float*)d_in[1];
  const float* wk = (const float*)d_in[2];
  const float* wv = (const float*)d_in[3];
  const float* wo = (const float*)d_in[4];
  // d_in[5]: attention_mask (causal triu k=1) — applied analytically.

  char* ws = (char*)d_ws;
  bf16* xb  = (bf16*)(ws + 0);           // 32 MB (4096x4096) — reused as AOb
  bf16* WqT = (bf16*)(ws + 33554432);    // 32 MB (4096x4096)
  bf16* WkT = (bf16*)(ws + 67108864);    //  8 MB (1024x4096)
  bf16* WvT = (bf16*)(ws + 75497472);    //  8 MB
  bf16* WoT = (bf16*)(ws + 83886080);    // 32 MB
  bf16* Qb  = (bf16*)(ws + 117440512);   // 32 MB (4096x4096)
  bf16* Kb  = (bf16*)(ws + 150994944);   //  8 MB (4096x1024)
  bf16* Vb  = (bf16*)(ws + 159383552);   //  8 MB
  bf16* VTb = (bf16*)(ws + 167772160);   //  8 MB (16x128x2048)
  float* tab = (float*)(ws + 176160768); //  1 MB (2048x64x2 f32)
  bf16* AOb = xb;                        // alias: x dead after projections

  convert_f32_bf16<<<16384, 256, 0, stream>>>(x, xb);
  transpose_f32_bf16<<<dim3(128, 128), 256, 0, stream>>>(wq, WqT, 4096, 4096);
  transpose_f32_bf16<<<dim3(32, 128), 256, 0, stream>>>(wk, WkT, 4096, 1024);
  transpose_f32_bf16<<<dim3(32, 128), 256, 0, stream>>>(wv, WvT, 4096, 1024);
  transpose_f32_bf16<<<dim3(128, 128), 256, 0, stream>>>(wo, WoT, 4096, 4096);
  rope_table_k<<<512, 256, 0, stream>>>(tab);

  gemm_bt<bf16><<<dim3(32, 32), 256, 0, stream>>>(xb, WqT, Qb, 4096, 4096, 4096);
  gemm_bt<bf16><<<dim3(8, 32), 256, 0, stream>>>(xb, WkT, Kb, 4096, 1024, 4096);
  gemm_bt<bf16><<<dim3(8, 32), 256, 0, stream>>>(xb, WvT, Vb, 4096, 1024, 4096);

  rope_apply<<<32768, 256, 0, stream>>>(Qb, tab, 32);
  rope_apply<<<8192, 256, 0, stream>>>(Kb, tab, 8);

  transpose_v<<<dim3(64, 4, 16), 256, 0, stream>>>(Vb, VTb);

  flash_attn<<<2048, 256, 0, stream>>>(Qb, Kb, VTb, AOb);

  gemm_bt<float><<<dim3(32, 32), 256, 0, stream>>>(AOb, WoT, (float*)d_out,
                                                   4096, 4096, 4096);
}

// Round 4
// 791.296 us; speedup vs baseline: 1.8945x; 1.8945x over previous
//
#include <hip/hip_runtime.h>
#include <hip/hip_bf16.h>
#include <math.h>

typedef __hip_bfloat16 bf16;
typedef short bf16x8 __attribute__((ext_vector_type(8)));
typedef float f32x4 __attribute__((ext_vector_type(4)));
typedef unsigned int u32;
typedef unsigned short u16;

#define GLD16(g, l)                                                            \
  __builtin_amdgcn_global_load_lds(                                            \
      (const __attribute__((address_space(1))) void*)(g),                      \
      (__attribute__((address_space(3))) void*)(l), 16, 0, 0)

// ------------------------------------------------------- f32 -> bf16 copy
__global__ void convert_f32_bf16(const float* __restrict__ in,
                                 bf16* __restrict__ out) {
  size_t i = ((size_t)blockIdx.x * 256 + threadIdx.x) * 4;
  float4 v = *(const float4*)(in + i);
  out[i + 0] = __float2bfloat16(v.x);
  out[i + 1] = __float2bfloat16(v.y);
  out[i + 2] = __float2bfloat16(v.z);
  out[i + 3] = __float2bfloat16(v.w);
}

// ----------------------------------------- f32 -> bf16 transposed weights
__global__ void transpose_f32_bf16(const float* __restrict__ in,
                                   bf16* __restrict__ out, int R, int C) {
  __shared__ bf16 tile[32][33];
  int tx = threadIdx.x & 31, ty = threadIdx.x >> 5;
  int c0 = blockIdx.x * 32, r0 = blockIdx.y * 32;
#pragma unroll
  for (int i = 0; i < 32; i += 8)
    tile[ty + i][tx] = __float2bfloat16(in[(size_t)(r0 + ty + i) * C + c0 + tx]);
  __syncthreads();
#pragma unroll
  for (int i = 0; i < 32; i += 8)
    out[(size_t)(c0 + ty + i) * R + r0 + tx] = tile[tx][ty + i];
}

// V: [4096][1024] bf16 (row = b*2048+t, col = kvh*128+d) -> VT: [16][128][2048]
__global__ void transpose_v(const bf16* __restrict__ V, bf16* __restrict__ VT) {
  __shared__ bf16 tile[32][33];
  int s = blockIdx.z, b = s >> 3, kvh = s & 7;
  int t0 = blockIdx.x * 32, d0 = blockIdx.y * 32;
  int tx = threadIdx.x & 31, ty = threadIdx.x >> 5;
#pragma unroll
  for (int i = 0; i < 32; i += 8)
    tile[ty + i][tx] = V[(size_t)(b * 2048 + t0 + ty + i) * 1024 + kvh * 128 + d0 + tx];
  __syncthreads();
#pragma unroll
  for (int i = 0; i < 32; i += 8)
    VT[((size_t)s * 128 + d0 + ty + i) * 2048 + t0 + tx] = tile[tx][ty + i];
}

// ---------------------------------------------------------------- RoPE
__global__ void rope_table_k(float* __restrict__ tab) {
  int idx = blockIdx.x * 256 + threadIdx.x;  // t*64 + i
  int t = idx >> 6, i = idx & 63;
  float theta = powf(10000.0f, -2.0f * (float)i / 128.0f);
  float ang = (float)t * theta;
  tab[idx * 2 + 0] = cosf(ang);
  tab[idx * 2 + 1] = sinf(ang);
}

__global__ void rope_apply(bf16* __restrict__ X, const float* __restrict__ tab,
                           int nheads) {
  size_t idx = (size_t)blockIdx.x * 256 + threadIdx.x;
  int i = (int)(idx & 63);
  size_t rest = idx >> 6;
  int h = (int)(rest % nheads);
  size_t r = rest / nheads;
  int t = (int)(r & 2047);
  float c = tab[(t * 64 + i) * 2 + 0];
  float s = tab[(t * 64 + i) * 2 + 1];
  bf16* p = X + r * ((size_t)nheads * 128) + h * 128 + 2 * i;
  float xr = __bfloat162float(p[0]), xi = __bfloat162float(p[1]);
  p[0] = __float2bfloat16(xr * c - xi * s);
  p[1] = __float2bfloat16(xr * s + xi * c);
}

// ---------------------------------------------------------------- GEMM (B^T)
template <typename OutT>
__global__ __launch_bounds__(256, 3) void gemm_bt(const bf16* __restrict__ A,
                                                  const bf16* __restrict__ BT,
                                                  OutT* __restrict__ C, int M,
                                                  int N, int K) {
  __shared__ bf16 As[128 * 32];
  __shared__ bf16 Bs[128 * 32];
  const int tid = threadIdx.x;
  const int lane = tid & 63, w = tid >> 6;
  const int wr = w >> 1, wc = w & 1;
  const int lr = lane & 15;
  const int ko = (lane >> 4) * 8;
  const int m0 = blockIdx.y * 128, n0 = blockIdx.x * 128;

  f32x4 acc[4][4];
#pragma unroll
  for (int m = 0; m < 4; ++m)
#pragma unroll
    for (int n = 0; n < 4; ++n)
#pragma unroll
      for (int j = 0; j < 4; ++j) acc[m][n][j] = 0.f;

  for (int k0 = 0; k0 < K; k0 += 32) {
#pragma unroll
    for (int i = 0; i < 2; ++i) {
      int c = i * 256 + tid;
      const bf16* ga = A + (size_t)(m0 + (c >> 2)) * K + k0 + (c & 3) * 8;
      const bf16* gb = BT + (size_t)(n0 + (c >> 2)) * K + k0 + (c & 3) * 8;
      GLD16(ga, As + c * 8);
      GLD16(gb, Bs + c * 8);
    }
    __syncthreads();
    bf16x8 af[4], bfr[4];
#pragma unroll
    for (int m = 0; m < 4; ++m)
      af[m] = *(const bf16x8*)(As + (wr * 64 + m * 16 + lr) * 32 + ko);
#pragma unroll
    for (int n = 0; n < 4; ++n)
      bfr[n] = *(const bf16x8*)(Bs + (wc * 64 + n * 16 + lr) * 32 + ko);
#pragma unroll
    for (int m = 0; m < 4; ++m)
#pragma unroll
      for (int n = 0; n < 4; ++n)
        acc[m][n] = __builtin_amdgcn_mfma_f32_16x16x32_bf16(af[m], bfr[n],
                                                            acc[m][n], 0, 0, 0);
    __syncthreads();
  }
#pragma unroll
  for (int m = 0; m < 4; ++m) {
    int row_base = m0 + wr * 64 + m * 16 + (lane >> 4) * 4;
#pragma unroll
    for (int n = 0; n < 4; ++n) {
      int col = n0 + wc * 64 + n * 16 + lr;
#pragma unroll
      for (int j = 0; j < 4; ++j) {
        float v = acc[m][n][j];
        if constexpr (sizeof(OutT) == 2)
          C[(size_t)(row_base + j) * N + col] = (OutT)__float2bfloat16(v);
        else
          C[(size_t)(row_base + j) * N + col] = (OutT)v;
      }
    }
  }
}

// ---------------------------------------------------------------- flash attn v2
// 128 q-rows/block (4 waves x 32), KVBLK=64, dbuf LDS K/VT (XOR-swizzled),
// swapped QK^T and PV (lane <-> q-row), P in registers via pack+shfl.
static __device__ inline u32 pack2_bf16(float a, float b) {
  u16 ua = __bfloat16_as_ushort(__float2bfloat16(a));
  u16 ub = __bfloat16_as_ushort(__float2bfloat16(b));
  return (u32)ua | ((u32)ub << 16);
}

__global__ __launch_bounds__(256) void flash_attn2(const bf16* __restrict__ Q,
                                                   const bf16* __restrict__ K,
                                                   const bf16* __restrict__ VT,
                                                   bf16* __restrict__ AO) {
  __shared__ bf16 Kbuf[2][64 * 128];   // [t][d], row stride 128 (swizzled)
  __shared__ bf16 Vbuf[2][128 * 64];   // [d][t], row stride 64 (swizzled)

  int bid = blockIdx.x;
  int lid = (bid & 7) * 128 + (bid >> 3);  // XCD-chunked swizzle (1024 % 8 == 0)
  int qt = 15 - (lid & 15);                // heavy tiles dispatch first
  int hq = (lid >> 4) & 3;
  int kvh = (lid >> 6) & 7;
  int b = lid >> 9;
  int h = kvh * 4 + hq;

  const int tid = threadIdx.x;
  const int lane = tid & 63, w = tid >> 6;
  const int lr = lane & 15, hi = lane >> 4;
  const int ko = hi * 8;
  const int qrow0 = qt * 128 + w * 32;
  const int nt = 2 * qt + 2;

  const bf16* Kg0 = K + (size_t)b * 2048 * 1024 + kvh * 128;
  const bf16* Vg0 = VT + (size_t)(b * 8 + kvh) * 128 * 2048;

  // Q fragments: lane <-> q-row (B-frag for swapped QK)
  bf16x8 qf[2][4];
#pragma unroll
  for (int mi = 0; mi < 2; ++mi) {
    const bf16* qb = Q + (size_t)(b * 2048 + qrow0 + mi * 16 + lr) * 4096 + h * 128;
#pragma unroll
    for (int kk = 0; kk < 4; ++kk) qf[mi][kk] = *(const bf16x8*)(qb + kk * 32 + ko);
  }

  f32x4 O[2][8];
  float m_[2], l_[2];
#pragma unroll
  for (int mi = 0; mi < 2; ++mi) {
    m_[mi] = -1e30f;
    l_[mi] = 0.f;
#pragma unroll
    for (int dd = 0; dd < 8; ++dd)
#pragma unroll
      for (int j = 0; j < 4; ++j) O[mi][dd][j] = 0.f;
  }

  const float scale = 0.08838834764831845f;  // 1/sqrt(128)

  auto STAGE = [&](int buf, int kv0) {
    bf16* Ks = &Kbuf[buf][0];
    bf16* Vs = &Vbuf[buf][0];
    const bf16* Kg = Kg0 + (size_t)kv0 * 1024;
    const bf16* Vg = Vg0 + kv0;
#pragma unroll
    for (int it = 0; it < 4; ++it) {  // K: 64 rows x 16 chunks of 16B
      int s = it * 256 + tid;
      int row = s >> 4, c = s & 15;
      GLD16(Kg + (size_t)row * 1024 + ((c ^ (row & 7)) << 3), Ks + s * 8);
    }
#pragma unroll
    for (int it = 0; it < 4; ++it) {  // VT: 128 rows x 8 chunks of 16B
      int s = it * 256 + tid;
      int row = s >> 3, c = s & 7;
      GLD16(Vg + (size_t)row * 2048 + ((c ^ (row & 7)) << 3), Vs + s * 8);
    }
  };

  STAGE(0, 0);
  __syncthreads();

  for (int t = 0; t < nt; ++t) {
    int kv0 = t * 64;
    if (t + 1 < nt) STAGE((t + 1) & 1, kv0 + 64);

    if (kv0 <= qrow0 + 31) {
      const bf16* Ks = &Kbuf[t & 1][0];
      const bf16* Vs = &Vbuf[t & 1][0];

      // ---- S^T = K . Q^T : lane <-> q = qrow0+mi*16+lr, elems k = cb*16+hi*4+j
      f32x4 Sx[2][4];
#pragma unroll
      for (int mi = 0; mi < 2; ++mi)
#pragma unroll
        for (int cb = 0; cb < 4; ++cb)
#pragma unroll
          for (int j = 0; j < 4; ++j) Sx[mi][cb][j] = 0.f;

#pragma unroll
      for (int cb = 0; cb < 4; ++cb) {
        bf16x8 kf[4];
#pragma unroll
        for (int kk = 0; kk < 4; ++kk)
          kf[kk] = *(const bf16x8*)(Ks + (cb * 16 + lr) * 128 +
                                    (((kk * 4 + hi) ^ (lr & 7)) << 3));
#pragma unroll
        for (int mi = 0; mi < 2; ++mi)
#pragma unroll
          for (int kk = 0; kk < 4; ++kk)
            Sx[mi][cb] = __builtin_amdgcn_mfma_f32_16x16x32_bf16(
                kf[kk], qf[mi][kk], Sx[mi][cb], 0, 0, 0);
      }

      bool domask = (kv0 + 63 > qrow0);
      u32 pau[2][2][4];  // [mi][kk2][e]
#pragma unroll
      for (int mi = 0; mi < 2; ++mi) {
        int q = qrow0 + mi * 16 + lr;
#pragma unroll
        for (int cb = 0; cb < 4; ++cb)
#pragma unroll
          for (int j = 0; j < 4; ++j) Sx[mi][cb][j] *= scale;
        if (domask) {
#pragma unroll
          for (int cb = 0; cb < 4; ++cb)
#pragma unroll
            for (int j = 0; j < 4; ++j)
              if (kv0 + cb * 16 + hi * 4 + j > q) Sx[mi][cb][j] = -1e30f;
        }
        float pm = -1e30f;
#pragma unroll
        for (int cb = 0; cb < 4; ++cb)
#pragma unroll
          for (int j = 0; j < 4; ++j) pm = fmaxf(pm, Sx[mi][cb][j]);
        pm = fmaxf(pm, __shfl_xor(pm, 16));
        pm = fmaxf(pm, __shfl_xor(pm, 32));
        float nm = fmaxf(m_[mi], pm);
        float rs = __expf(m_[mi] - nm);
        float ps = 0.f;
#pragma unroll
        for (int cb = 0; cb < 4; ++cb)
#pragma unroll
          for (int j = 0; j < 4; ++j) {
            float p = __expf(Sx[mi][cb][j] - nm);
            Sx[mi][cb][j] = p;
            ps += p;
          }
        ps += __shfl_xor(ps, 16);
        ps += __shfl_xor(ps, 32);
        l_[mi] = l_[mi] * rs + ps;
        m_[mi] = nm;
#pragma unroll
        for (int dd = 0; dd < 8; ++dd)
#pragma unroll
          for (int j = 0; j < 4; ++j) O[mi][dd][j] *= rs;

        // pack P to bf16 pairs: vp[cb*2+jp] holds k = cb*16+hi*4+{2jp,2jp+1}
        u32 vp[8];
#pragma unroll
        for (int cb = 0; cb < 4; ++cb)
#pragma unroll
          for (int jp = 0; jp < 2; ++jp)
            vp[cb * 2 + jp] = pack2_bf16(Sx[mi][cb][2 * jp], Sx[mi][cb][2 * jp + 1]);

        // redistribute: pa elem e of kk2 needs k-pair t = kk2*32 + hi*8 + 2e
        // source lane: hi_src = 2*(hi&1) + (e>>1); needed vp idx =
        // 4*kk2 + 2*(hi_dest>>1) + (e&1). Destinations hi and hi+2 pull
        // DIFFERENT vp entries from the SAME source lane -> must shuffle both
        // candidates and select at the destination (round-3 bug: selected on
        // the source lane using the source's hi).
#pragma unroll
        for (int kk2 = 0; kk2 < 2; ++kk2)
#pragma unroll
          for (int e = 0; e < 4; ++e) {
            int src = lr + ((hi & 1) << 5) + ((e >> 1) << 4);
            u32 va = (u32)__shfl((int)vp[4 * kk2 + (e & 1)], src);
            u32 vb = (u32)__shfl((int)vp[4 * kk2 + 2 + (e & 1)], src);
            pau[mi][kk2][e] = (hi & 2) ? vb : va;
          }
      }

      // ---- O^T += VT . P^T : lane <-> q, rows d = dd*16+hi*4+j
#pragma unroll
      for (int dd = 0; dd < 8; ++dd) {
        bf16x8 vf[2];
#pragma unroll
        for (int kk2 = 0; kk2 < 2; ++kk2)
          vf[kk2] = *(const bf16x8*)(Vs + (dd * 16 + lr) * 64 +
                                     (((kk2 * 4 + hi) ^ (lr & 7)) << 3));
#pragma unroll
        for (int mi = 0; mi < 2; ++mi)
#pragma unroll
          for (int kk2 = 0; kk2 < 2; ++kk2) {
            union { u32 u[4]; bf16x8 h; } cv;
#pragma unroll
            for (int e = 0; e < 4; ++e) cv.u[e] = pau[mi][kk2][e];
            O[mi][dd] = __builtin_amdgcn_mfma_f32_16x16x32_bf16(
                vf[kk2], cv.h, O[mi][dd], 0, 0, 0);
          }
      }
    }
    __syncthreads();
  }

  // epilogue: AO[q][h*128 + d], 8B packed stores
#pragma unroll
  for (int mi = 0; mi < 2; ++mi) {
    float inv = 1.0f / l_[mi];
    bf16* outp = AO + (size_t)(b * 2048 + qrow0 + mi * 16 + lr) * 4096 + h * 128;
#pragma unroll
    for (int dd = 0; dd < 8; ++dd) {
      union { u16 s[4]; unsigned long long v; } pk;
#pragma unroll
      for (int j = 0; j < 4; ++j)
        pk.s[j] = __bfloat16_as_ushort(__float2bfloat16(O[mi][dd][j] * inv));
      *(unsigned long long*)(outp + dd * 16 + hi * 4) = pk.v;
    }
  }
}

// ---------------------------------------------------------------- launch
extern "C" void kernel_launch(void* const* d_in, const int* in_sizes, int n_in,
                              void* d_out, int out_size, void* d_ws,
                              size_t ws_size, hipStream_t stream) {
  const float* x = (const float*)d_in[0];
  const float* wq = (const float*)d_in[1];
  const float* wk = (const float*)d_in[2];
  const float* wv = (const float*)d_in[3];
  const float* wo = (const float*)d_in[4];

  char* ws = (char*)d_ws;
  bf16* xb  = (bf16*)(ws + 0);           // 32 MB — reused as AOb
  bf16* WqT = (bf16*)(ws + 33554432);    // 32 MB
  bf16* WkT = (bf16*)(ws + 67108864);    //  8 MB
  bf16* WvT = (bf16*)(ws + 75497472);    //  8 MB
  bf16* WoT = (bf16*)(ws + 83886080);    // 32 MB
  bf16* Qb  = (bf16*)(ws + 117440512);   // 32 MB
  bf16* Kb  = (bf16*)(ws + 150994944);   //  8 MB
  bf16* Vb  = (bf16*)(ws + 159383552);   //  8 MB
  bf16* VTb = (bf16*)(ws + 167772160);   //  8 MB (16x128x2048)
  float* tab = (float*)(ws + 176160768); //  1 MB
  bf16* AOb = xb;

  convert_f32_bf16<<<16384, 256, 0, stream>>>(x, xb);
  transpose_f32_bf16<<<dim3(128, 128), 256, 0, stream>>>(wq, WqT, 4096, 4096);
  transpose_f32_bf16<<<dim3(32, 128), 256, 0, stream>>>(wk, WkT, 4096, 1024);
  transpose_f32_bf16<<<dim3(32, 128), 256, 0, stream>>>(wv, WvT, 4096, 1024);
  transpose_f32_bf16<<<dim3(128, 128), 256, 0, stream>>>(wo, WoT, 4096, 4096);
  rope_table_k<<<512, 256, 0, stream>>>(tab);

  gemm_bt<bf16><<<dim3(32, 32), 256, 0, stream>>>(xb, WqT, Qb, 4096, 4096, 4096);
  gemm_bt<bf16><<<dim3(8, 32), 256, 0, stream>>>(xb, WkT, Kb, 4096, 1024, 4096);
  gemm_bt<bf16><<<dim3(8, 32), 256, 0, stream>>>(xb, WvT, Vb, 4096, 1024, 4096);

  rope_apply<<<32768, 256, 0, stream>>>(Qb, tab, 32);
  rope_apply<<<8192, 256, 0, stream>>>(Kb, tab, 8);

  transpose_v<<<dim3(64, 4, 16), 256, 0, stream>>>(Vb, VTb);

  flash_attn2<<<1024, 256, 0, stream>>>(Qb, Kb, VTb, AOb);

  gemm_bt<float><<<dim3(32, 32), 256, 0, stream>>>(AOb, WoT, (float*)d_out,
                                                   4096, 4096, 4096);
}